// Round 8
// baseline (141.840 us; speedup 1.0000x reference)
//
#include <hip/hip_runtime.h>
#include <math.h>

typedef unsigned short u16t;
typedef __attribute__((ext_vector_type(8))) __bf16 bf16x8;
typedef __attribute__((ext_vector_type(4))) float f32x4;
typedef __attribute__((ext_vector_type(16))) float f32x16;
typedef __attribute__((ext_vector_type(4))) unsigned short u16x4;

__device__ __forceinline__ u16t f2bf(float f) {
  union { float f; unsigned u; } v; v.f = f;
  return (u16t)((v.u + 0x7FFFu + ((v.u >> 16) & 1u)) >> 16);
}
__device__ __forceinline__ float bf2f(u16t u) {
  union { unsigned u; float f; } v; v.u = (unsigned)u << 16; return v.f;
}

// async global->LDS, 16B per lane; LDS dest linear (wave-uniform base + lane*16)
__device__ __forceinline__ void gload_lds16(const void* g, void* l) {
  __builtin_amdgcn_global_load_lds(
      (__attribute__((address_space(1))) void*)(uintptr_t)g,
      (__attribute__((address_space(3))) void*)(unsigned)(uintptr_t)l,
      16, 0, 0);
}

// v_permlane32_swap_b32 (mapping verified R4-R6)
__device__ __forceinline__ void plswap(unsigned &a, unsigned &b) {
  asm("v_permlane32_swap_b32 %0, %1" : "+v"(a), "+v"(b));
}

// ---------------- fused f32 -> bf16 convert of target|source|value ----------------
__global__ __launch_bounds__(256) void k_cvt3(const float* __restrict__ t0,
                                              const float* __restrict__ s0,
                                              const float* __restrict__ v0,
                                              u16t* __restrict__ out) {
  int row = blockIdx.x, t = threadIdx.x;
  const float* src = row < 4096 ? t0 + ((size_t)row << 10)
                   : row < 6144 ? s0 + ((size_t)(row - 4096) << 10)
                                : v0 + ((size_t)(row - 6144) << 10);
  f32x4 x = *reinterpret_cast<const f32x4*>(src + t * 4);
  u16x4 y;
#pragma unroll
  for (int j = 0; j < 4; j++) y[j] = f2bf(x[j]);
  *reinterpret_cast<u16x4*>(out + ((size_t)row << 10) + t * 4) = y;
}

// ---------------- fused 4x weight transpose f32[1024][1024] -> bf16 transposed ----
__global__ __launch_bounds__(256) void k_wtrans4(const float* __restrict__ Wq,
                                                 const float* __restrict__ Wk,
                                                 const float* __restrict__ Wv,
                                                 const float* __restrict__ Wo,
                                                 u16t* __restrict__ dstAll) {
  __shared__ u16t tile[64][68];
  int z = blockIdx.z;
  const float* in = z == 0 ? Wq : z == 1 ? Wk : z == 2 ? Wv : Wo;
  u16t* out = dstAll + ((size_t)z << 20);
  int r0 = blockIdx.y * 64, c0 = blockIdx.x * 64;
  int t = threadIdx.x;
  int rr = t >> 4, q4 = (t & 15) * 4;
#pragma unroll
  for (int i = 0; i < 4; i++) {
    int r = rr + i * 16;
    f32x4 x = *reinterpret_cast<const f32x4*>(&in[(size_t)(r0 + r) * 1024 + c0 + q4]);
#pragma unroll
    for (int j = 0; j < 4; j++) tile[r][q4 + j] = f2bf(x[j]);
  }
  __syncthreads();
#pragma unroll
  for (int i = 0; i < 4; i++) {
    int c = rr + i * 16;
    u16x4 y;
#pragma unroll
    for (int j = 0; j < 4; j++) y[j] = tile[q4 + j][c];
    *reinterpret_cast<u16x4*>(&out[(size_t)(c0 + c) * 1024 + r0 + q4]) = y;
  }
}

// ---------------- bf16 transpose [2048][1024] -> [1024][2048] (V) ----------------
__global__ __launch_bounds__(256) void k_vtrans(const u16t* __restrict__ in,
                                                u16t* __restrict__ out) {
  __shared__ u16t tile[64][68];
  int r0 = blockIdx.y * 64, c0 = blockIdx.x * 64;
  int t = threadIdx.x;
  int rr = t >> 4, q4 = (t & 15) * 4;
#pragma unroll
  for (int i = 0; i < 4; i++) {
    int r = rr + i * 16;
    u16x4 x = *reinterpret_cast<const u16x4*>(&in[(size_t)(r0 + r) * 1024 + c0 + q4]);
#pragma unroll
    for (int j = 0; j < 4; j++) tile[r][q4 + j] = x[j];
  }
  __syncthreads();
#pragma unroll
  for (int i = 0; i < 4; i++) {
    int c = rr + i * 16;
    u16x4 y;
#pragma unroll
    for (int j = 0; j < 4; j++) y[j] = tile[q4 + j][c];
    *reinterpret_cast<u16x4*>(&out[(size_t)(c0 + c) * 2048 + r0 + q4]) = y;
  }
}

// ---------------- column sums of kn and vbf (bf16 [2048][1024]) -> f32[1024] ----
__global__ __launch_bounds__(256) void k_colsum2(const u16t* __restrict__ kn,
                                                 const u16t* __restrict__ vb,
                                                 float* __restrict__ Kcol,
                                                 float* __restrict__ Vcol) {
  int t = threadIdx.x, c4 = t * 4, r0 = blockIdx.x * 32;
  float sk[4] = {0.f, 0.f, 0.f, 0.f}, sv[4] = {0.f, 0.f, 0.f, 0.f};
  for (int r = r0; r < r0 + 32; r++) {
    u16x4 a = *reinterpret_cast<const u16x4*>(&kn[((size_t)r << 10) + c4]);
    u16x4 b = *reinterpret_cast<const u16x4*>(&vb[((size_t)r << 10) + c4]);
#pragma unroll
    for (int j = 0; j < 4; j++) { sk[j] += bf2f(a[j]); sv[j] += bf2f(b[j]); }
  }
#pragma unroll
  for (int j = 0; j < 4; j++) {
    atomicAdd(&Kcol[c4 + j], sk[j]);
    atomicAdd(&Vcol[c4 + j], sv[j]);
  }
}

// ---------------- 128x128x(K=1024) MFMA core, counted-vmcnt 2-barrier pipeline ----
__device__ __forceinline__ void gemm128_acc(const u16t* __restrict__ A,
                                            const u16t* __restrict__ Bt,
                                            int m0, int n0, f32x4 acc[4][4]) {
  __shared__ __align__(16) u16t As[2][128 * 64];
  __shared__ __align__(16) u16t Bs[2][128 * 64];
  int t = threadIdx.x, lane = t & 63, w = t >> 6;
  int l15 = lane & 15, l16 = lane >> 4;
  int wr = w >> 1, wc = w & 1;
  int srow = t >> 3;
  int slc = ((t & 7) ^ (srow & 7)) << 3;

#define GSTAGE(KT, NB) do {                                                      \
    _Pragma("unroll")                                                            \
    for (int i = 0; i < 4; i++) {                                                \
      int row_ = srow + i * 32;                                                  \
      int c16_ = (t + i * 256) * 16;                                             \
      gload_lds16(A + ((size_t)(m0 + row_) << 10) + (KT) + slc, (char*)As[NB] + c16_); \
      gload_lds16(Bt + ((size_t)(n0 + row_) << 10) + (KT) + slc, (char*)Bs[NB] + c16_); \
    } } while (0)

  GSTAGE(0, 0);
  for (int ki = 0; ki < 16; ki++) {
    int cur = ki & 1;
    if (ki < 15) {
      GSTAGE((ki + 1) << 6, cur ^ 1);
      asm volatile("s_waitcnt vmcnt(8)" ::: "memory");
    } else {
      asm volatile("s_waitcnt vmcnt(0)" ::: "memory");
    }
    __builtin_amdgcn_s_barrier();
    asm volatile("" ::: "memory");
#pragma unroll
    for (int kk = 0; kk < 2; kk++) {
      bf16x8 af[4], bfr[4];
#pragma unroll
      for (int m = 0; m < 4; m++) {
        int ar = wr * 64 + m * 16 + l15;
        af[m] = *(const bf16x8*)((char*)As[cur] + ar * 128 + ((kk * 64 + l16 * 16) ^ ((ar & 7) << 4)));
      }
#pragma unroll
      for (int n = 0; n < 4; n++) {
        int br = wc * 64 + n * 16 + l15;
        bfr[n] = *(const bf16x8*)((char*)Bs[cur] + br * 128 + ((kk * 64 + l16 * 16) ^ ((br & 7) << 4)));
      }
#pragma unroll
      for (int m = 0; m < 4; m++)
#pragma unroll
        for (int n = 0; n < 4; n++)
          acc[m][n] = __builtin_amdgcn_mfma_f32_16x16x32_bf16(af[m], bfr[n], acc[m][n], 0, 0, 0);
    }
    __builtin_amdgcn_s_barrier();
    asm volatile("" ::: "memory");
  }
#undef GSTAGE
}

// QKV GEMM with fused bias + ELU + per-head L2-norm epilogue -> bf16
__global__ __launch_bounds__(256) void k_gemm_qkv(const u16t* __restrict__ A,
                                                  const u16t* __restrict__ Wt,
                                                  const float* __restrict__ b0,
                                                  const float* __restrict__ b1,
                                                  const float* __restrict__ b2,
                                                  u16t* __restrict__ out) {
  int m0 = blockIdx.y * 128, n0 = blockIdx.x * 128;
  int seg = (m0 >= 6144) ? 2 : (m0 >= 4096) ? 1 : 0;
  const float* bias = (seg == 0) ? b0 : (seg == 1) ? b1 : b2;
  f32x4 acc[4][4] = {};
  gemm128_acc(A, Wt + ((size_t)seg << 20), m0, n0, acc);

  int t = threadIdx.x, lane = t & 63, w = t >> 6;
  int l15 = lane & 15, l16 = lane >> 4;
  int wr = w >> 1, wc = w & 1;
  float bb[4];
#pragma unroll
  for (int n = 0; n < 4; n++) bb[n] = bias[n0 + wc * 64 + n * 16 + l15];
  if (seg < 2) {
    float scale0 = (seg == 0) ? 0.125f : 1.f;
#pragma unroll
    for (int m = 0; m < 4; m++) {
#pragma unroll
      for (int r = 0; r < 4; r++) {
        float e[4]; float ss = 0.f;
#pragma unroll
        for (int n = 0; n < 4; n++) {
          float x = acc[m][n][r] + bb[n];
          e[n] = x > 0.f ? x : (__expf(x) - 1.f);
          ss += e[n] * e[n];
        }
        ss += __shfl_xor(ss, 1); ss += __shfl_xor(ss, 2);
        ss += __shfl_xor(ss, 4); ss += __shfl_xor(ss, 8);
        float rinv = rsqrtf(ss) * scale0;
        int row = m0 + wr * 64 + m * 16 + l16 * 4 + r;
#pragma unroll
        for (int n = 0; n < 4; n++)
          out[((size_t)row << 10) + n0 + wc * 64 + n * 16 + l15] = f2bf(e[n] * rinv);
      }
    }
  } else {
#pragma unroll
    for (int m = 0; m < 4; m++) {
      int row = m0 + wr * 64 + m * 16 + l16 * 4;
#pragma unroll
      for (int n = 0; n < 4; n++) {
        int col = n0 + wc * 64 + n * 16 + l15;
#pragma unroll
        for (int r = 0; r < 4; r++)
          out[((size_t)(row + r) << 10) + col] = f2bf(acc[m][n][r] + bb[n]);
      }
    }
  }
}

// O-projection GEMM: ctx bf16 @ Wo^T + bo -> f32
__global__ __launch_bounds__(256) void k_gemm_o(const u16t* __restrict__ A,
                                                const u16t* __restrict__ Wt,
                                                const float* __restrict__ bias,
                                                float* __restrict__ C) {
  int m0 = blockIdx.y * 128, n0 = blockIdx.x * 128;
  f32x4 acc[4][4] = {};
  gemm128_acc(A, Wt, m0, n0, acc);
  int t = threadIdx.x, lane = t & 63, w = t >> 6;
  int l15 = lane & 15, l16 = lane >> 4;
  int wr = w >> 1, wc = w & 1;
#pragma unroll
  for (int n = 0; n < 4; n++) {
    int col = n0 + wc * 64 + n * 16 + l15;
    float bb = bias[col];
#pragma unroll
    for (int m = 0; m < 4; m++) {
      int row = m0 + wr * 64 + m * 16 + l16 * 4;
#pragma unroll
      for (int r = 0; r < 4; r++)
        C[((size_t)(row + r) << 10) + col] = acc[m][n][r] + bb;
    }
  }
}

// ---------------- fused attention v4: linear softmax ----------------
// exp(s) ~= 1+s (|s|<=0.128): O = Vcol + sum mfma(s_bf16, V); rsum = 2048 + qn.Kcol.
// 2 waves x 64 q = 128 q/block; grid (16,32); shared 32KB dbuf staging;
// counted vmcnt(8) + 2 raw barriers per chunk; 32 useful MFMA/chunk/wave.
__global__ __launch_bounds__(128) void k_attn(const u16t* __restrict__ qn,
                                              const u16t* __restrict__ kn,
                                              const u16t* __restrict__ vT,
                                              const float* __restrict__ Kcol,
                                              const float* __restrict__ Vcol,
                                              u16t* __restrict__ ctx) {
  __shared__ __align__(16) u16t kls[2][4096];
  __shared__ __align__(16) u16t vls[2][4096];
  int bh = blockIdx.y, b = bh >> 4, h = bh & 15;
  int qt = blockIdx.x;
  int t = threadIdx.x, lane = t & 63, w = t >> 6;
  int l31 = lane & 31, hi = lane >> 5;

  // Q B-frags: qf[qtile][ks]; qn pre-scaled by 0.125
  const u16t* qp0 = qn + ((size_t)(b * 2048 + qt * 128 + w * 64 + l31) << 10) + (h << 6) + hi * 8;
  bf16x8 qf[2][4];
#pragma unroll
  for (int q2 = 0; q2 < 2; q2++)
#pragma unroll
    for (int ks = 0; ks < 4; ks++)
      qf[q2][ks] = *(const bf16x8*)(qp0 + (q2 << 15) + ks * 16);

  // rsum dot: rdot[qt] = sum_e qn[q][e] * Kcol[h*64+e]  (lane has 32 of 64 e)
  float rdot0 = 0.f, rdot1 = 0.f;
#pragma unroll
  for (int ks = 0; ks < 4; ks++) {
    const float* kc = &Kcol[(h << 6) + ks * 16 + hi * 8];
    union { bf16x8 v; u16t u[8]; } a0, a1;
    a0.v = qf[0][ks]; a1.v = qf[1][ks];
#pragma unroll
    for (int j = 0; j < 8; j++) {
      float kcj = kc[j];
      rdot0 = fmaf(bf2f(a0.u[j]), kcj, rdot0);
      rdot1 = fmaf(bf2f(a1.u[j]), kcj, rdot1);
    }
  }
  rdot0 += __shfl_xor(rdot0, 32);
  rdot1 += __shfl_xor(rdot1, 32);

  // staging source (lane-invariant across chunks)
  int r16 = t >> 3, c8 = t & 7;
  int sce = (c8 ^ (r16 & 7)) << 3;
  const u16t* kbase = kn + (size_t)r16 * 1024 + (h << 6) + sce;          // + tc<<16 + j<<14
  const u16t* vbase = vT + (((size_t)(h * 64 + r16)) << 11) + sce;       // + tc<<6  + j<<15
  int ldst = t * 16;

  // frag read addrs
  int kxor = (l31 & 7) << 4;
  int va0[4], va1[4];
#pragma unroll
  for (int ks = 0; ks < 4; ks++) {
    int off = (ks * 32 + hi * 16) ^ kxor;
    va0[ks] = l31 * 128 + off;
    va1[ks] = (32 + l31) * 128 + off;
  }

  f32x16 o00 = {}, o01 = {}, o10 = {}, o11 = {};
  const f32x16 fz = {};

#define MF32(A, B, C) __builtin_amdgcn_mfma_f32_32x32x16_bf16(A, B, C, 0, 0, 0)

#define ASTAGE(TC, NB) do {                                                   \
    _Pragma("unroll")                                                         \
    for (int j = 0; j < 4; j++)                                               \
      gload_lds16(kbase + ((TC) << 16) + (j << 14), (char*)kls[NB] + ldst + (j << 11)); \
    _Pragma("unroll")                                                         \
    for (int j = 0; j < 4; j++)                                               \
      gload_lds16(vbase + ((TC) << 6) + (j << 15), (char*)vls[NB] + ldst + (j << 11)); \
  } while (0)

#define PACK(S, FA, FB) do {                                                  \
    unsigned mm[8];                                                           \
    _Pragma("unroll")                                                         \
    for (int i = 0; i < 8; i++)                                               \
      asm("v_cvt_pk_bf16_f32 %0, %1, %2" : "=v"(mm[i]) : "v"(S[2 * i]), "v"(S[2 * i + 1])); \
    plswap(mm[0], mm[2]); plswap(mm[1], mm[3]);                               \
    plswap(mm[4], mm[6]); plswap(mm[5], mm[7]);                               \
    union { unsigned u[4]; bf16x8 v; } A_, B_;                                \
    A_.u[0] = mm[0]; A_.u[1] = mm[1]; A_.u[2] = mm[2]; A_.u[3] = mm[3];       \
    B_.u[0] = mm[4]; B_.u[1] = mm[5]; B_.u[2] = mm[6]; B_.u[3] = mm[7];       \
    FA = A_.v; FB = B_.v;                                                     \
  } while (0)

  ASTAGE(0, 0);
  for (int tc = 0; tc < 32; tc++) {
    int cur = tc & 1;
    if (tc < 31) {
      ASTAGE(tc + 1, cur ^ 1);
      asm volatile("s_waitcnt vmcnt(8)" ::: "memory");
    } else {
      asm volatile("s_waitcnt vmcnt(0)" ::: "memory");
    }
    __builtin_amdgcn_s_barrier();
    asm volatile("" ::: "memory");
    const char* kb = (const char*)kls[cur];
    const char* vb = (const char*)vls[cur];

    f32x16 s00, s01, s10, s11;
#pragma unroll
    for (int ks = 0; ks < 4; ks++) {
      bf16x8 a0 = *(const bf16x8*)(kb + va0[ks]);
      bf16x8 a1 = *(const bf16x8*)(kb + va1[ks]);
      s00 = MF32(a0, qf[0][ks], ks == 0 ? fz : s00);
      s01 = MF32(a0, qf[1][ks], ks == 0 ? fz : s01);
      s10 = MF32(a1, qf[0][ks], ks == 0 ? fz : s10);
      s11 = MF32(a1, qf[1][ks], ks == 0 ? fz : s11);
    }
    bf16x8 pf0[4], pf1[4];
    PACK(s00, pf0[0], pf0[1]); PACK(s10, pf0[2], pf0[3]);
    PACK(s01, pf1[0], pf1[1]); PACK(s11, pf1[2], pf1[3]);

    __builtin_amdgcn_s_setprio(1);
#pragma unroll
    for (int ks = 0; ks < 4; ks++) {
      bf16x8 v0 = *(const bf16x8*)(vb + va0[ks]);
      bf16x8 v1 = *(const bf16x8*)(vb + va1[ks]);
      o00 = MF32(pf0[ks], v0, o00);
      o01 = MF32(pf0[ks], v1, o01);
      o10 = MF32(pf1[ks], v0, o10);
      o11 = MF32(pf1[ks], v1, o11);
    }
    __builtin_amdgcn_s_setprio(0);
    __builtin_amdgcn_s_barrier();
    asm volatile("" ::: "memory");
  }

  // epilogue: O = (o + Vcol) / (2048 + rdot[q])
  float vc0 = Vcol[(h << 6) + l31];
  float vc1 = Vcol[(h << 6) + 32 + l31];
  size_t rbase = (size_t)(b * 2048 + qt * 128 + w * 64);
#pragma unroll
  for (int r = 0; r < 16; r++) {
    int q = (r & 3) + 8 * (r >> 2) + 4 * hi;
    float ri0 = 1.f / (2048.f + __shfl(rdot0, q));
    float ri1 = 1.f / (2048.f + __shfl(rdot1, q));
    u16t* cp0 = ctx + ((rbase + q) << 10) + (h << 6) + l31;
    u16t* cp1 = ctx + ((rbase + 32 + q) << 10) + (h << 6) + l31;
    cp0[0]  = f2bf((o00[r] + vc0) * ri0);
    cp0[32] = f2bf((o01[r] + vc1) * ri0);
    cp1[0]  = f2bf((o10[r] + vc0) * ri1);
    cp1[32] = f2bf((o11[r] + vc1) * ri1);
  }
#undef PACK
#undef ASTAGE
#undef MF32
}

// ---------------- residual + LayerNorm ----------------
__global__ __launch_bounds__(256) void k_out_ln(const float* __restrict__ Hh,
                                                const float* __restrict__ target,
                                                const float* __restrict__ g,
                                                const float* __restrict__ bb,
                                                float* __restrict__ out) {
  __shared__ float s_s[4], s_ss[4];
  int row = blockIdx.x, t = threadIdx.x, w = t >> 6;
  f32x4 hv = *reinterpret_cast<const f32x4*>(&Hh[(size_t)row * 1024 + t * 4]);
  f32x4 tv = *reinterpret_cast<const f32x4*>(&target[(size_t)row * 1024 + t * 4]);
  f32x4 x;
#pragma unroll
  for (int j = 0; j < 4; j++) x[j] = hv[j] + tv[j];
  float s = x[0] + x[1] + x[2] + x[3];
  float ss = x[0] * x[0] + x[1] * x[1] + x[2] * x[2] + x[3] * x[3];
#pragma unroll
  for (int m = 1; m < 64; m <<= 1) { s += __shfl_xor(s, m); ss += __shfl_xor(ss, m); }
  if ((t & 63) == 0) { s_s[w] = s; s_ss[w] = ss; }
  __syncthreads();
  s = s_s[0] + s_s[1] + s_s[2] + s_s[3];
  ss = s_ss[0] + s_ss[1] + s_ss[2] + s_ss[3];
  float mu = s * (1.f / 1024.f);
  float var = ss * (1.f / 1024.f) - mu * mu;
  float rsn = rsqrtf(var + 1e-12f);
  f32x4 gv = *reinterpret_cast<const f32x4*>(&g[t * 4]);
  f32x4 bv = *reinterpret_cast<const f32x4*>(&bb[t * 4]);
  f32x4 o;
#pragma unroll
  for (int j = 0; j < 4; j++) o[j] = (x[j] - mu) * rsn * gv[j] + bv[j];
  *reinterpret_cast<f32x4*>(&out[(size_t)row * 1024 + t * 4]) = o;
}

extern "C" void kernel_launch(void* const* d_in, const int* in_sizes, int n_in,
                              void* d_out, int out_size, void* d_ws, size_t ws_size,
                              hipStream_t stream) {
  const float* target = (const float*)d_in[0];
  const float* source = (const float*)d_in[1];
  const float* value  = (const float*)d_in[2];
  const float* Wq = (const float*)d_in[3];
  const float* bq = (const float*)d_in[4];
  const float* Wk = (const float*)d_in[5];
  const float* bk = (const float*)d_in[6];
  const float* Wv = (const float*)d_in[7];
  const float* bvp = (const float*)d_in[8];
  const float* Wo = (const float*)d_in[9];
  const float* bo = (const float*)d_in[10];
  const float* lng = (const float*)d_in[11];
  const float* lnb = (const float*)d_in[12];
  float* out = (float*)d_out;
  char* ws = (char*)d_ws;
  const size_t MB = 1u << 20;

  u16t* abf   = (u16t*)ws;                       // [0,16) bf16 target|source|value
  u16t* Wt    = (u16t*)(ws + 16 * MB);           // [16,24) 4x transposed weights
  u16t* Wot   = Wt + ((size_t)3 << 20);
  u16t* qkvnb = (u16t*)(ws + 24 * MB);           // [24,40) qn|kn|vbf
  u16t* qnb   = qkvnb;
  u16t* knb   = qkvnb + ((size_t)4096 << 10);
  u16t* vbf   = qkvnb + ((size_t)6144 << 10);
  u16t* vTb   = (u16t*)(ws + 40 * MB);           // [40,44) vT [1024][2048]
  u16t* ctxb  = (u16t*)(ws + 44 * MB);           // [44,52)
  float* Hf   = (float*)(ws + 52 * MB);          // [52,68)
  float* Kcolf = (float*)(ws + 68 * MB);         // 4KB
  float* Vcolf = Kcolf + 1024;                   // 4KB

  k_cvt3<<<dim3(8192), 256, 0, stream>>>(target, source, value, abf);
  k_wtrans4<<<dim3(16, 16, 4), 256, 0, stream>>>(Wq, Wk, Wv, Wo, Wt);
  hipMemsetAsync(Kcolf, 0, 8192, stream);
  k_gemm_qkv<<<dim3(8, 64), 256, 0, stream>>>(abf, Wt, bq, bk, bvp, qkvnb);
  k_colsum2<<<dim3(64), 256, 0, stream>>>(knb, vbf, Kcolf, Vcolf);
  k_vtrans<<<dim3(16, 32), 256, 0, stream>>>(vbf, vTb);
  k_attn<<<dim3(16, 32), 128, 0, stream>>>(qnb, knb, vTb, Kcolf, Vcolf, ctxb);
  k_gemm_o<<<dim3(8, 32), 256, 0, stream>>>(ctxb, Wot, bo, Hf);
  k_out_ln<<<dim3(4096), 256, 0, stream>>>(Hf, target, lng, lnb, out);
}

// Round 10
// 111.845 us; speedup vs baseline: 1.2682x; 1.2682x over previous
//
#include <hip/hip_runtime.h>
#include <math.h>

typedef unsigned short u16t;
typedef __attribute__((ext_vector_type(8))) __bf16 bf16x8;
typedef __attribute__((ext_vector_type(4))) float f32x4;
typedef __attribute__((ext_vector_type(16))) float f32x16;
typedef __attribute__((ext_vector_type(4))) unsigned short u16x4;

__device__ __forceinline__ u16t f2bf(float f) {
  union { float f; unsigned u; } v; v.f = f;
  return (u16t)((v.u + 0x7FFFu + ((v.u >> 16) & 1u)) >> 16);
}
__device__ __forceinline__ float bf2f(u16t u) {
  union { unsigned u; float f; } v; v.u = (unsigned)u << 16; return v.f;
}

// async global->LDS, 16B per lane; LDS dest linear (wave-uniform base + lane*16)
__device__ __forceinline__ void gload_lds16(const void* g, void* l) {
  __builtin_amdgcn_global_load_lds(
      (__attribute__((address_space(1))) void*)(uintptr_t)g,
      (__attribute__((address_space(3))) void*)(unsigned)(uintptr_t)l,
      16, 0, 0);
}

__device__ __forceinline__ f32x16 mf32(bf16x8 a, bf16x8 b, f32x16 c) {
  return __builtin_amdgcn_mfma_f32_32x32x16_bf16(a, b, c, 0, 0, 0);
}

// ---------------- fused f32 -> bf16 convert of target|source|value ----------------
__global__ __launch_bounds__(256) void k_cvt3(const float* __restrict__ t0,
                                              const float* __restrict__ s0,
                                              const float* __restrict__ v0,
                                              u16t* __restrict__ out) {
  int row = blockIdx.x, t = threadIdx.x;
  const float* src = row < 4096 ? t0 + ((size_t)row << 10)
                   : row < 6144 ? s0 + ((size_t)(row - 4096) << 10)
                                : v0 + ((size_t)(row - 6144) << 10);
  f32x4 x = *reinterpret_cast<const f32x4*>(src + t * 4);
  u16x4 y;
#pragma unroll
  for (int j = 0; j < 4; j++) y[j] = f2bf(x[j]);
  *reinterpret_cast<u16x4*>(out + ((size_t)row << 10) + t * 4) = y;
}

// ---------------- fused 4x weight transpose f32[1024][1024] -> bf16 transposed ----
__global__ __launch_bounds__(256) void k_wtrans4(const float* __restrict__ Wq,
                                                 const float* __restrict__ Wk,
                                                 const float* __restrict__ Wv,
                                                 const float* __restrict__ Wo,
                                                 u16t* __restrict__ dstAll) {
  __shared__ u16t tile[64][68];
  int z = blockIdx.z;
  const float* in = z == 0 ? Wq : z == 1 ? Wk : z == 2 ? Wv : Wo;
  u16t* out = dstAll + ((size_t)z << 20);
  int r0 = blockIdx.y * 64, c0 = blockIdx.x * 64;
  int t = threadIdx.x;
  int rr = t >> 4, q4 = (t & 15) * 4;
#pragma unroll
  for (int i = 0; i < 4; i++) {
    int r = rr + i * 16;
    f32x4 x = *reinterpret_cast<const f32x4*>(&in[(size_t)(r0 + r) * 1024 + c0 + q4]);
#pragma unroll
    for (int j = 0; j < 4; j++) tile[r][q4 + j] = f2bf(x[j]);
  }
  __syncthreads();
#pragma unroll
  for (int i = 0; i < 4; i++) {
    int c = rr + i * 16;
    u16x4 y;
#pragma unroll
    for (int j = 0; j < 4; j++) y[j] = tile[q4 + j][c];
    *reinterpret_cast<u16x4*>(&out[(size_t)(c0 + c) * 1024 + r0 + q4]) = y;
  }
}

// ---------------- dual bf16 transpose [2048][1024] -> [1024][2048]: kn->knT, vbf->vT ----
__global__ __launch_bounds__(256) void k_vtrans2(const u16t* __restrict__ in0,
                                                 const u16t* __restrict__ in1,
                                                 u16t* __restrict__ o0,
                                                 u16t* __restrict__ o1) {
  __shared__ u16t tile[64][68];
  int z = blockIdx.z;
  const u16t* in = z ? in1 : in0;
  u16t* out = z ? o1 : o0;
  int r0 = blockIdx.y * 64, c0 = blockIdx.x * 64;
  int t = threadIdx.x;
  int rr = t >> 4, q4 = (t & 15) * 4;
#pragma unroll
  for (int i = 0; i < 4; i++) {
    int r = rr + i * 16;
    u16x4 x = *reinterpret_cast<const u16x4*>(&in[(size_t)(r0 + r) * 1024 + c0 + q4]);
#pragma unroll
    for (int j = 0; j < 4; j++) tile[r][q4 + j] = x[j];
  }
  __syncthreads();
#pragma unroll
  for (int i = 0; i < 4; i++) {
    int c = rr + i * 16;
    u16x4 y;
#pragma unroll
    for (int j = 0; j < 4; j++) y[j] = tile[q4 + j][c];
    *reinterpret_cast<u16x4*>(&out[(size_t)(c0 + c) * 2048 + r0 + q4]) = y;
  }
}

// ---------------- column sums of kn and vbf -> f32[1024] each ----------------
__global__ __launch_bounds__(256) void k_colsum2(const u16t* __restrict__ kn,
                                                 const u16t* __restrict__ vb,
                                                 float* __restrict__ Kcol,
                                                 float* __restrict__ Vcol) {
  int t = threadIdx.x, c4 = t * 4, r0 = blockIdx.x * 32;
  float sk[4] = {0.f, 0.f, 0.f, 0.f}, sv[4] = {0.f, 0.f, 0.f, 0.f};
  for (int r = r0; r < r0 + 32; r++) {
    u16x4 a = *reinterpret_cast<const u16x4*>(&kn[((size_t)r << 10) + c4]);
    u16x4 b = *reinterpret_cast<const u16x4*>(&vb[((size_t)r << 10) + c4]);
#pragma unroll
    for (int j = 0; j < 4; j++) { sk[j] += bf2f(a[j]); sv[j] += bf2f(b[j]); }
  }
#pragma unroll
  for (int j = 0; j < 4; j++) {
    atomicAdd(&Kcol[c4 + j], sk[j]);
    atomicAdd(&Vcol[c4 + j], sv[j]);
  }
}

// ---------------- k_ktv: per-head M_h = kn_h^T @ v_h  (stored transposed, bf16) ----
// MT layout per head: [65][64] u16t (stride 4160): rows 0..63 = MT[e2][e1] = M[e1][e2];
// row 64 = Kcol_h bf16. grid (4 quadrants, 16 heads); 4 waves split K=2048.
__global__ __launch_bounds__(256) void k_ktv(const u16t* __restrict__ knT,
                                             const u16t* __restrict__ vT,
                                             const float* __restrict__ Kcol,
                                             u16t* __restrict__ MT) {
  __shared__ float sls[4][1024];
  int qd = blockIdx.x, h = blockIdx.y;
  int e1t = qd >> 1, e2t = qd & 1;
  int t = threadIdx.x, lane = t & 63, w = t >> 6;
  int l31 = lane & 31, hi = lane >> 5;
  const u16t* ap = knT + (((size_t)((h << 6) + e1t * 32 + l31)) << 11) + w * 512 + hi * 8;
  const u16t* bp = vT  + (((size_t)((h << 6) + e2t * 32 + l31)) << 11) + w * 512 + hi * 8;
  f32x16 acc = {};
#pragma unroll
  for (int k = 0; k < 32; k++) {
    bf16x8 a = *(const bf16x8*)(ap + k * 16);
    bf16x8 b = *(const bf16x8*)(bp + k * 16);
    acc = mf32(a, b, acc);
  }
#pragma unroll
  for (int r = 0; r < 16; r++) {
    int e1l = (r & 3) + 8 * (r >> 2) + 4 * hi;
    sls[w][e1l * 32 + l31] = acc[r];
  }
  __syncthreads();
#pragma unroll
  for (int i = 0; i < 4; i++) {
    int idx = t * 4 + i;
    int e1 = idx >> 5, e2 = idx & 31;
    float s = sls[0][idx] + sls[1][idx] + sls[2][idx] + sls[3][idx];
    MT[h * 4160 + (e2t * 32 + e2) * 64 + e1t * 32 + e1] = f2bf(s);
  }
  if (qd == 0 && t < 64)
    MT[h * 4160 + 4096 + t] = f2bf(Kcol[(h << 6) + t]);
}

// ---------------- k_ctx: ctx = (qn8 @ M + Vcol) / (2048 + qn8.Kcol) -> bf16 ----
// grid 128 row-tiles of 32; 4 waves; wave w handles heads w*4..w*4+3.
__global__ __launch_bounds__(256) void k_ctx(const u16t* __restrict__ qn8,
                                             const u16t* __restrict__ MT,
                                             const float* __restrict__ Vcol,
                                             u16t* __restrict__ ctx) {
  int rt = blockIdx.x;
  int t = threadIdx.x, lane = t & 63, w = t >> 6;
  int l31 = lane & 31, hi = lane >> 5;
  int rowb = rt * 32;
  const u16t* qbase = qn8 + (((size_t)(rowb + l31)) << 10) + hi * 8;
  const f32x16 fz = {};
#pragma unroll
  for (int hh = 0; hh < 4; hh++) {
    int h = w * 4 + hh;
    const u16t* mbase = MT + h * 4160;
    bf16x8 af[4], kf[4];
#pragma unroll
    for (int ks = 0; ks < 4; ks++) {
      af[ks] = *(const bf16x8*)(qbase + (h << 6) + ks * 16);
      kf[ks] = *(const bf16x8*)(mbase + 4096 + ks * 16 + hi * 8);
    }
    f32x16 a0, a1, rd;
#pragma unroll
    for (int ks = 0; ks < 4; ks++) {
      bf16x8 b0 = *(const bf16x8*)(mbase + l31 * 64 + ks * 16 + hi * 8);
      bf16x8 b1 = *(const bf16x8*)(mbase + (32 + l31) * 64 + ks * 16 + hi * 8);
      a0 = mf32(af[ks], b0, ks ? a0 : fz);
      a1 = mf32(af[ks], b1, ks ? a1 : fz);
      rd = mf32(af[ks], kf[ks], ks ? rd : fz);
    }
    float vc0 = Vcol[(h << 6) + l31];
    float vc1 = Vcol[(h << 6) + 32 + l31];
#pragma unroll
    for (int r = 0; r < 16; r++) {
      int row = rowb + (r & 3) + 8 * (r >> 2) + 4 * hi;
      float ri = 1.f / (2048.f + rd[r]);
      u16t* cp = ctx + (((size_t)row) << 10) + (h << 6) + l31;
      cp[0]  = f2bf((a0[r] + vc0) * ri);
      cp[32] = f2bf((a1[r] + vc1) * ri);
    }
  }
}

// ---------------- 128x128x(K=1024) MFMA core, counted-vmcnt 2-barrier pipeline ----
__device__ __forceinline__ void gemm128_acc(const u16t* __restrict__ A,
                                            const u16t* __restrict__ Bt,
                                            int m0, int n0, f32x4 acc[4][4]) {
  __shared__ __align__(16) u16t As[2][128 * 64];
  __shared__ __align__(16) u16t Bs[2][128 * 64];
  int t = threadIdx.x, lane = t & 63, w = t >> 6;
  int l15 = lane & 15, l16 = lane >> 4;
  int wr = w >> 1, wc = w & 1;
  int srow = t >> 3;
  int slc = ((t & 7) ^ (srow & 7)) << 3;

#define GSTAGE(KT, NB) do {                                                      \
    _Pragma("unroll")                                                            \
    for (int i = 0; i < 4; i++) {                                                \
      int row_ = srow + i * 32;                                                  \
      int c16_ = (t + i * 256) * 16;                                             \
      gload_lds16(A + ((size_t)(m0 + row_) << 10) + (KT) + slc, (char*)As[NB] + c16_); \
      gload_lds16(Bt + ((size_t)(n0 + row_) << 10) + (KT) + slc, (char*)Bs[NB] + c16_); \
    } } while (0)

  GSTAGE(0, 0);
  for (int ki = 0; ki < 16; ki++) {
    int cur = ki & 1;
    if (ki < 15) {
      GSTAGE((ki + 1) << 6, cur ^ 1);
      asm volatile("s_waitcnt vmcnt(8)" ::: "memory");
    } else {
      asm volatile("s_waitcnt vmcnt(0)" ::: "memory");
    }
    __builtin_amdgcn_s_barrier();
    asm volatile("" ::: "memory");
#pragma unroll
    for (int kk = 0; kk < 2; kk++) {
      bf16x8 af[4], bfr[4];
#pragma unroll
      for (int m = 0; m < 4; m++) {
        int ar = wr * 64 + m * 16 + l15;
        af[m] = *(const bf16x8*)((char*)As[cur] + ar * 128 + ((kk * 64 + l16 * 16) ^ ((ar & 7) << 4)));
      }
#pragma unroll
      for (int n = 0; n < 4; n++) {
        int br = wc * 64 + n * 16 + l15;
        bfr[n] = *(const bf16x8*)((char*)Bs[cur] + br * 128 + ((kk * 64 + l16 * 16) ^ ((br & 7) << 4)));
      }
#pragma unroll
      for (int m = 0; m < 4; m++)
#pragma unroll
        for (int n = 0; n < 4; n++)
          acc[m][n] = __builtin_amdgcn_mfma_f32_16x16x32_bf16(af[m], bfr[n], acc[m][n], 0, 0, 0);
    }
    __builtin_amdgcn_s_barrier();
    asm volatile("" ::: "memory");
  }
#undef GSTAGE
}

// QKV GEMM with fused bias + ELU + per-head L2-norm epilogue -> bf16
__global__ __launch_bounds__(256) void k_gemm_qkv(const u16t* __restrict__ A,
                                                  const u16t* __restrict__ Wt,
                                                  const float* __restrict__ b0,
                                                  const float* __restrict__ b1,
                                                  const float* __restrict__ b2,
                                                  u16t* __restrict__ out) {
  int m0 = blockIdx.y * 128, n0 = blockIdx.x * 128;
  int seg = (m0 >= 6144) ? 2 : (m0 >= 4096) ? 1 : 0;
  const float* bias = (seg == 0) ? b0 : (seg == 1) ? b1 : b2;
  f32x4 acc[4][4] = {};
  gemm128_acc(A, Wt + ((size_t)seg << 20), m0, n0, acc);

  int t = threadIdx.x, lane = t & 63, w = t >> 6;
  int l15 = lane & 15, l16 = lane >> 4;
  int wr = w >> 1, wc = w & 1;
  float bb[4];
#pragma unroll
  for (int n = 0; n < 4; n++) bb[n] = bias[n0 + wc * 64 + n * 16 + l15];
  if (seg < 2) {
    float scale0 = (seg == 0) ? 0.125f : 1.f;
#pragma unroll
    for (int m = 0; m < 4; m++) {
#pragma unroll
      for (int r = 0; r < 4; r++) {
        float e[4]; float ss = 0.f;
#pragma unroll
        for (int n = 0; n < 4; n++) {
          float x = acc[m][n][r] + bb[n];
          e[n] = x > 0.f ? x : (__expf(x) - 1.f);
          ss += e[n] * e[n];
        }
        ss += __shfl_xor(ss, 1); ss += __shfl_xor(ss, 2);
        ss += __shfl_xor(ss, 4); ss += __shfl_xor(ss, 8);
        float rinv = rsqrtf(ss) * scale0;
        int row = m0 + wr * 64 + m * 16 + l16 * 4 + r;
#pragma unroll
        for (int n = 0; n < 4; n++)
          out[((size_t)row << 10) + n0 + wc * 64 + n * 16 + l15] = f2bf(e[n] * rinv);
      }
    }
  } else {
#pragma unroll
    for (int m = 0; m < 4; m++) {
      int row = m0 + wr * 64 + m * 16 + l16 * 4;
#pragma unroll
      for (int n = 0; n < 4; n++) {
        int col = n0 + wc * 64 + n * 16 + l15;
#pragma unroll
        for (int r = 0; r < 4; r++)
          out[((size_t)(row + r) << 10) + col] = f2bf(acc[m][n][r] + bb[n]);
      }
    }
  }
}

// O-projection GEMM: ctx bf16 @ Wo^T + bo -> f32
__global__ __launch_bounds__(256) void k_gemm_o(const u16t* __restrict__ A,
                                                const u16t* __restrict__ Wt,
                                                const float* __restrict__ bias,
                                                float* __restrict__ C) {
  int m0 = blockIdx.y * 128, n0 = blockIdx.x * 128;
  f32x4 acc[4][4] = {};
  gemm128_acc(A, Wt, m0, n0, acc);
  int t = threadIdx.x, lane = t & 63, w = t >> 6;
  int l15 = lane & 15, l16 = lane >> 4;
  int wr = w >> 1, wc = w & 1;
#pragma unroll
  for (int n = 0; n < 4; n++) {
    int col = n0 + wc * 64 + n * 16 + l15;
    float bb = bias[col];
#pragma unroll
    for (int m = 0; m < 4; m++) {
      int row = m0 + wr * 64 + m * 16 + l16 * 4;
#pragma unroll
      for (int r = 0; r < 4; r++)
        C[((size_t)(row + r) << 10) + col] = acc[m][n][r] + bb;
    }
  }
}

// ---------------- residual + LayerNorm ----------------
__global__ __launch_bounds__(256) void k_out_ln(const float* __restrict__ Hh,
                                                const float* __restrict__ target,
                                                const float* __restrict__ g,
                                                const float* __restrict__ bb,
                                                float* __restrict__ out) {
  __shared__ float s_s[4], s_ss[4];
  int row = blockIdx.x, t = threadIdx.x, w = t >> 6;
  f32x4 hv = *reinterpret_cast<const f32x4*>(&Hh[(size_t)row * 1024 + t * 4]);
  f32x4 tv = *reinterpret_cast<const f32x4*>(&target[(size_t)row * 1024 + t * 4]);
  f32x4 x;
#pragma unroll
  for (int j = 0; j < 4; j++) x[j] = hv[j] + tv[j];
  float s = x[0] + x[1] + x[2] + x[3];
  float ss = x[0] * x[0] + x[1] * x[1] + x[2] * x[2] + x[3] * x[3];
#pragma unroll
  for (int m = 1; m < 64; m <<= 1) { s += __shfl_xor(s, m); ss += __shfl_xor(ss, m); }
  if ((t & 63) == 0) { s_s[w] = s; s_ss[w] = ss; }
  __syncthreads();
  s = s_s[0] + s_s[1] + s_s[2] + s_s[3];
  ss = s_ss[0] + s_ss[1] + s_ss[2] + s_ss[3];
  float mu = s * (1.f / 1024.f);
  float var = ss * (1.f / 1024.f) - mu * mu;
  float rsn = rsqrtf(var + 1e-12f);
  f32x4 gv = *reinterpret_cast<const f32x4*>(&g[t * 4]);
  f32x4 bv = *reinterpret_cast<const f32x4*>(&bb[t * 4]);
  f32x4 o;
#pragma unroll
  for (int j = 0; j < 4; j++) o[j] = (x[j] - mu) * rsn * gv[j] + bv[j];
  *reinterpret_cast<f32x4*>(&out[(size_t)row * 1024 + t * 4]) = o;
}

extern "C" void kernel_launch(void* const* d_in, const int* in_sizes, int n_in,
                              void* d_out, int out_size, void* d_ws, size_t ws_size,
                              hipStream_t stream) {
  const float* target = (const float*)d_in[0];
  const float* source = (const float*)d_in[1];
  const float* value  = (const float*)d_in[2];
  const float* Wq = (const float*)d_in[3];
  const float* bq = (const float*)d_in[4];
  const float* Wk = (const float*)d_in[5];
  const float* bk = (const float*)d_in[6];
  const float* Wv = (const float*)d_in[7];
  const float* bvp = (const float*)d_in[8];
  const float* Wo = (const float*)d_in[9];
  const float* bo = (const float*)d_in[10];
  const float* lng = (const float*)d_in[11];
  const float* lnb = (const float*)d_in[12];
  float* out = (float*)d_out;
  char* ws = (char*)d_ws;
  const size_t MB = 1u << 20;

  // ws layout (~64 MB + 144 KB):
  //  [0,16)  abf bf16 [8192][1024] (dead after qkv; ctxb overlays [0,8))
  //  [16,24) Wt bf16 4x transposed weights
  //  [24,40) qkvnb: qn8 | kn | vbf
  //  [40,44) knT bf16 [1024][2048]
  //  [44,48) vT  bf16 [1024][2048]
  //  [48,64) Hf f32 [4096][1024]
  //  [64MB+) Kcol f32 1024 | Vcol f32 1024 | MT bf16 16x4160
  u16t* abf   = (u16t*)ws;
  u16t* ctxb  = (u16t*)ws;                        // overlays abf after qkv
  u16t* Wt    = (u16t*)(ws + 16 * MB);
  u16t* Wot   = Wt + ((size_t)3 << 20);
  u16t* qkvnb = (u16t*)(ws + 24 * MB);
  u16t* qnb   = qkvnb;
  u16t* knb   = qkvnb + ((size_t)4096 << 10);
  u16t* vbf   = qkvnb + ((size_t)6144 << 10);
  u16t* knT   = (u16t*)(ws + 40 * MB);
  u16t* vTb   = (u16t*)(ws + 44 * MB);
  float* Hf   = (float*)(ws + 48 * MB);
  float* Kcolf = (float*)(ws + 64 * MB);
  float* Vcolf = Kcolf + 1024;
  u16t* MTb   = (u16t*)(Vcolf + 1024);

  k_cvt3<<<dim3(8192), 256, 0, stream>>>(target, source, value, abf);
  k_wtrans4<<<dim3(16, 16, 4), 256, 0, stream>>>(Wq, Wk, Wv, Wo, Wt);
  hipMemsetAsync(Kcolf, 0, 8192, stream);
  k_gemm_qkv<<<dim3(8, 64), 256, 0, stream>>>(abf, Wt, bq, bk, bvp, qkvnb);
  k_colsum2<<<dim3(64), 256, 0, stream>>>(knb, vbf, Kcolf, Vcolf);
  k_vtrans2<<<dim3(16, 32, 2), 256, 0, stream>>>(knb, vbf, knT, vTb);
  k_ktv<<<dim3(4, 16), 256, 0, stream>>>(knT, vTb, Kcolf, MTb);
  k_ctx<<<dim3(128), 256, 0, stream>>>(qnb, MTb, Vcolf, ctxb);
  k_gemm_o<<<dim3(8, 32), 256, 0, stream>>>(ctxb, Wot, bo, Hf);
  k_out_ln<<<dim3(4096), 256, 0, stream>>>(Hf, target, lng, lnb, out);
}